// Round 10
// baseline (1819.854 us; speedup 1.0000x reference)
//
#include <hip/hip_runtime.h>
#include <cstdint>

typedef unsigned int u32;
typedef unsigned long long u64;

#define BATCH 8
#define H 1024
#define W 1024
#define HW (H*W)
#define NPIX (BATCH*HW)
#define KTOP 2048
#define NBIN 8192
#define KEYCAP 8192
#define CAPP 131072
#define CAPC 65536
#define TARGET 2080

#define D9 1e-3f
#define DV 1e-4f

// fused tile geometry
#define TOX 64
#define TOY 32
#define CCX 72          // conv cols: tx0-4 .. tx0+67
#define CCY 36          // conv rows: ty0-2 .. ty0+33
#define SCSTR 73
#define SIROWS 68       // input rows ty0-18 .. ty0+49
#define SICOLS 104      // input cols tx0-20 .. tx0+83
#define SISTR 104
#define NIT 11          // ceil(CCX*CCY / 256)

// ws layout (bytes); [0, OFF_PASS) memset to 0 each launch
#define OFF_MISC 0                          // u32: pass[0..8) chk[8..16) kcnt[16..24) cut[24..32)
#define OFF_HIST 4096                       // u32[8][NBIN] = 256 KB
#define OFF_PASS (OFF_HIST + BATCH*NBIN*4)
#define OFF_CHK  (OFF_PASS + BATCH*CAPP*4)
#define OFF_KEY  (OFF_CHK  + BATCH*CAPC*4)

#define LD4(p) (*reinterpret_cast<const float4*>(p))
#define ST4(p,v) (*reinterpret_cast<float4*>(p) = (v))

// ---------------- f64 dilated conv + relu (IDENTICAL to green rounds 3-9) ----------------
__device__ __forceinline__ double conv_resp_f64(
    const float* __restrict__ in, const float* __restrict__ wc,
    const float* __restrict__ wsw, int b, int y, int x)
{
  const float* base = in + (size_t)b * 3 * HW;
  const float* Sp = base;
  const float* Cp = base + HW;
  double resp = 0.0;
  const int dil[3] = {1, 4, 16};
  #pragma unroll
  for (int di = 0; di < 3; ++di) {
    int d = dil[di];
    double ac = 0.0, as = 0.0;
    #pragma unroll
    for (int ky = 0; ky < 3; ++ky) {
      int yy = y + (ky - 1) * d;
      bool yok = ((unsigned)yy < (unsigned)H);
      #pragma unroll
      for (int kx = 0; kx < 3; ++kx) {
        int xx = x + (kx - 1) * d;
        bool ok = yok && ((unsigned)xx < (unsigned)W);
        double a  = ok ? (double)Cp[yy * W + xx] : 0.0;
        double s2 = ok ? (double)Sp[yy * W + xx] : 0.0;
        ac = fma(a,  (double)wc[di * 9 + ky * 3 + kx], ac);
        as = fma(s2, (double)wsw[di * 9 + ky * 3 + kx], as);
      }
    }
    resp += ac;
    resp += as;
  }
  return resp > 0.0 ? resp : 0.0;
}

__device__ __forceinline__ u64 make_key(double val, int p) {
  u64 dbits = __double_as_longlong(val);
  return (dbits & ~0xFFFFFull) | (u64)((~(u32)p) & 0xFFFFFu);
}

// ---------------- stage one channel into LDS with zero-filled halo ----------------
__device__ __forceinline__ void stage_ch(
    float* sIn, const float* __restrict__ src, int tx0, int ty0, int tid)
{
  const int NG = (SIROWS * SICOLS) / 4;  // 1768 float4 groups
  for (int g = tid; g < NG; g += 256) {
    int r = g / (SICOLS / 4);
    int c4 = (g - r * (SICOLS / 4)) * 4;
    int gy = ty0 - 18 + r;
    int gx0 = tx0 - 20 + c4;
    float4 v = make_float4(0.f, 0.f, 0.f, 0.f);
    if ((unsigned)gy < (unsigned)H) {
      if (gx0 >= 0 && gx0 + 3 < W) {
        v = LD4(src + gy * W + gx0);
      } else {
        float t[4];
        #pragma unroll
        for (int i = 0; i < 4; ++i) {
          int gx = gx0 + i;
          t[i] = ((unsigned)gx < (unsigned)W) ? src[gy * W + gx] : 0.f;
        }
        v = make_float4(t[0], t[1], t[2], t[3]);
      }
    }
    *reinterpret_cast<float4*>(&sIn[r * SISTR + c4]) = v;
  }
}

// ---------------- accumulate 27 taps (one channel) from LDS into part[] ----------------
__device__ __forceinline__ void accum_taps(
    const float* sIn, const float* __restrict__ wp, float* part, int tid)
{
  #pragma unroll
  for (int k = 0; k < NIT; ++k) {
    int idx = k * 256 + tid;
    if (idx < CCX * CCY) {
      int cr = idx / CCX;
      int cc = idx - cr * CCX;
      float a = 0.f;
      #pragma unroll
      for (int di = 0; di < 3; ++di) {
        const int d = (di == 0) ? 1 : (di == 1) ? 4 : 16;
        float ac = 0.f;
        #pragma unroll
        for (int ky = 0; ky < 3; ++ky) {
          const float* rp = sIn + (cr + 16 + (ky - 1) * d) * SISTR + cc + 16;
          float t0 = rp[-d];
          float t1 = rp[0];
          float t2 = rp[d];
          ac = fmaf(t0, wp[di * 9 + ky * 3 + 0], ac);
          ac = fmaf(t1, wp[di * 9 + ky * 3 + 1], ac);
          ac = fmaf(t2, wp[di * 9 + ky * 3 + 2], ac);
        }
        a += ac;
      }
      part[k] += a;
    }
  }
}

// ---------------- fused kernel: stage->conv(LDS)->outputs + in-LDS screen ----------------
__global__ __launch_bounds__(256) void conv_screen_kernel(
    const float* __restrict__ in, const float* __restrict__ wc,
    const float* __restrict__ wsw, float* __restrict__ out0,
    float* __restrict__ convr, u32* __restrict__ passlist,
    u32* __restrict__ checklist, u32* __restrict__ hist, u32* __restrict__ misc)
{
  __shared__ float sIn[SIROWS * SISTR];
  __shared__ float sconv[CCY][SCSTR];

  int b = blockIdx.z;
  int tx0 = blockIdx.x * TOX;
  int ty0 = blockIdx.y * TOY;
  int tid = threadIdx.x;
  const float* Sp = in + (size_t)b * 3 * HW;
  const float* Cp = Sp + HW;
  const float* Rp = Sp + 2 * HW;
  float* ob = out0 + (size_t)b * 3 * HW;
  float* cb = convr + (size_t)b * HW;

  // ---- elementwise outputs for the 64x32 tile (f4) ----
  #pragma unroll
  for (int r = 0; r < (TOX * TOY) / 4 / 256; ++r) {
    int idx = r * 256 + tid;
    int ly = idx / (TOX / 4);
    int lx4 = (idx - ly * (TOX / 4)) * 4;
    int p0 = (ty0 + ly) * W + tx0 + lx4;
    float4 S4 = LD4(Sp + p0);
    float4 C4 = LD4(Cp + p0);
    float4 R4 = LD4(Rp + p0);
    ST4(ob + p0, S4);
    ST4(ob + HW + p0, C4);
    float4 E4 = make_float4(expf(R4.x) - 1.f, expf(R4.y) - 1.f,
                            expf(R4.z) - 1.f, expf(R4.w) - 1.f);
    ST4(ob + 2 * HW + p0, E4);
  }

  // ---- phase A: C channel ----
  float part[NIT];
  #pragma unroll
  for (int k = 0; k < NIT; ++k) part[k] = 0.f;

  stage_ch(sIn, Cp, tx0, ty0, tid);
  __syncthreads();
  accum_taps(sIn, wc, part, tid);
  __syncthreads();

  // ---- phase B: S channel (reuse same LDS) ----
  stage_ch(sIn, Sp, tx0, ty0, tid);
  __syncthreads();
  accum_taps(sIn, wsw, part, tid);

  // ---- finalize: relu -> sconv (+ global convr core) ----
  #pragma unroll
  for (int k = 0; k < NIT; ++k) {
    int idx = k * 256 + tid;
    if (idx < CCX * CCY) {
      int cr = idx / CCX;
      int cc = idx - cr * CCX;
      float rv = fmaxf(part[k], 0.f);
      sconv[cr][cc] = rv;
      if (cr >= 2 && cr <= CCY - 3 && cc >= 4 && cc <= CCX - 5) {
        int gy = ty0 - 2 + cr, gx = tx0 - 4 + cc;
        cb[gy * W + gx] = rv;
      }
    }
  }
  __syncthreads();

  // ---- in-LDS screen, wave-aggregated appends ----
  int lane = tid & 63;
  for (int r = 0; r < (TOX * TOY) / 256; ++r) {
    int idx = r * 256 + tid;
    int ly = idx >> 6;
    int lx = idx & 63;
    int x = tx0 + lx, y = ty0 + ly;
    bool act = (y >= 5 && y <= H - 6 && x >= 5 && x <= W - 6);

    bool cand = false, pass = false;
    float val = 0.f;
    if (act) {
      float vs0[5], vs1[5], vs2[5];
      #pragma unroll
      for (int j = 0; j < 5; ++j) {
        int c = lx + 2 + j;
        float a0 = sconv[ly + 0][c];
        float a1 = sconv[ly + 1][c];
        float a2 = sconv[ly + 2][c];
        float a3 = sconv[ly + 3][c];
        float a4 = sconv[ly + 4][c];
        vs0[j] = a0 + a1 + a2;
        vs1[j] = a1 + a2 + a3;
        vs2[j] = a2 + a3 + a4;
      }
      float hs0[3], hs1[3], hs2[3];
      #pragma unroll
      for (int j = 0; j < 3; ++j) {
        hs0[j] = vs0[j] + vs0[j + 1] + vs0[j + 2];
        hs1[j] = vs1[j] + vs1[j + 1] + vs1[j + 2];
        hs2[j] = vs2[j] + vs2[j + 1] + vs2[j + 2];
      }
      float sc9 = hs1[1];
      val = sconv[ly + 2][lx + 4];
      float m9 = fmaxf(fmaxf(fmaxf(hs0[0], hs0[1]), fmaxf(hs0[2], hs1[0])),
                       fmaxf(fmaxf(hs1[2], hs2[0]), fmaxf(hs2[1], hs2[2])));
      cand = !((sc9 < 0.9f - D9) || (sc9 < m9 - D9) || (val < 0.1f - DV));
      pass = cand && (sc9 > 0.9f + D9) && (sc9 >= m9 + D9) && (val > 0.1f + DV);
    }

    u64 pm = __ballot(pass);
    if (pass) {
      int leader = __ffsll((unsigned long long)pm) - 1;
      u32 base = 0;
      if (lane == leader) base = atomicAdd(&misc[b], (u32)__popcll(pm));
      base = __shfl(base, leader);
      u32 rk = (u32)__popcll(pm & ((1ull << lane) - 1ull));
      if (base + rk < CAPP) passlist[(size_t)b * CAPP + base + rk] = (u32)(y * W + x);
      atomicAdd(&hist[b * NBIN + (__float_as_uint(val) >> 19)], 1u);
    }
    bool chk = cand && !pass;
    u64 cm = __ballot(chk);
    if (chk) {
      int leader = __ffsll((unsigned long long)cm) - 1;
      u32 base = 0;
      if (lane == leader) base = atomicAdd(&misc[8 + b], (u32)__popcll(cm));
      base = __shfl(base, leader);
      u32 rk = (u32)__popcll(cm & ((1ull << lane) - 1ull));
      if (base + rk < CAPC) checklist[(size_t)b * CAPC + base + rk] = (u32)(y * W + x);
    }
  }
}

// ---------------- suffix-scan hist -> f32 cut (rank TARGET, one-bin slack) ------
__global__ __launch_bounds__(1024) void cutscan_kernel(
    const u32* __restrict__ hist, u32* __restrict__ misc)
{
  __shared__ u32 sfx[NBIN];
  int b = blockIdx.x;
  int tid = threadIdx.x;
  const u32* h = hist + b * NBIN;
  #pragma unroll
  for (int k = 0; k < 8; ++k) sfx[tid * 8 + k] = h[tid * 8 + k];
  __syncthreads();

  for (int off = 1; off < NBIN; off <<= 1) {
    u32 t[8];
    #pragma unroll
    for (int k = 0; k < 8; ++k) {
      int i = tid * 8 + k;
      t[k] = (i + off < NBIN) ? sfx[i + off] : 0u;
    }
    __syncthreads();
    #pragma unroll
    for (int k = 0; k < 8; ++k) sfx[tid * 8 + k] += t[k];
    __syncthreads();
  }

  if (sfx[0] < TARGET) return;

  #pragma unroll
  for (int k = 0; k < 8; ++k) {
    int i = tid * 8 + k;
    u32 s = sfx[i];
    u32 nxt = (i + 1 < NBIN) ? sfx[i + 1] : 0u;
    if (s >= TARGET && nxt < TARGET) {
      u32 cutbin = (i > 0) ? (u32)(i - 1) : 0u;
      misc[24 + b] = cutbin << 19;
    }
  }
}

// ---------------- exact f64 keys for pass-peaks above cut ----------------
__global__ __launch_bounds__(256) void keygen_kernel(
    const float* __restrict__ in, const float* __restrict__ wc,
    const float* __restrict__ wsw, const float* __restrict__ convr,
    const u32* __restrict__ passlist, u32* __restrict__ misc, u64* __restrict__ keybuf)
{
  int gtid = blockIdx.x * 256 + threadIdx.x;
  int gsz = gridDim.x * 256;
  for (int b = 0; b < BATCH; ++b) {
    int np = (int)min(misc[b], (u32)CAPP);
    u32 cutb = misc[24 + b];
    for (int i = gtid; i < np; i += gsz) {
      int p = (int)passlist[(size_t)b * CAPP + i];
      float fv = convr[(size_t)b * HW + p];
      if (__float_as_uint(fv) < cutb) continue;
      double v = conv_resp_f64(in, wc, wsw, b, p >> 10, p & (W - 1));
      u32 pos = atomicAdd(&misc[16 + b], 1u);
      if (pos < KEYCAP) keybuf[(size_t)b * KEYCAP + pos] = make_key(v, p);
    }
  }
}

// ---------------- exact f64 recheck, one wave per uncertain pixel ----------------
__global__ __launch_bounds__(256) void recheck_kernel(
    const float* __restrict__ in, const float* __restrict__ wc,
    const float* __restrict__ wsw, const float* __restrict__ convr,
    const u32* __restrict__ checklist, u32* __restrict__ misc, u64* __restrict__ keybuf)
{
  int wid = (blockIdx.x * 256 + threadIdx.x) >> 6;
  int lane = threadIdx.x & 63;
  int nw = (gridDim.x * 256) >> 6;

  for (int b = 0; b < BATCH; ++b) {
    int nc = (int)min(misc[8 + b], (u32)CAPC);
    u32 cutb = misc[24 + b];
    for (int i = wid; i < nc; i += nw) {
      int p = (int)checklist[(size_t)b * CAPC + i];
      int y = p >> 10, x = p & (W - 1);

      double v = 0.0;
      if (lane < 25)
        v = conv_resp_f64(in, wc, wsw, b, y + lane / 5 - 2, x + lane % 5 - 2);

      double c[25];
      #pragma unroll
      for (int k = 0; k < 25; ++k) c[k] = __shfl(v, k);

      double cs0[5], cs1[5], cs2[5];
      #pragma unroll
      for (int j = 0; j < 5; ++j) {
        cs0[j] = c[0 + j] + c[5 + j] + c[10 + j];
        cs1[j] = c[5 + j] + c[10 + j] + c[15 + j];
        cs2[j] = c[10 + j] + c[15 + j] + c[20 + j];
      }
      double val = c[12];

      double sc = (cs1[1] + cs1[2] + cs1[3]) * (1.0 / 9.0);
      if (!(sc > 0.1)) continue;
      bool pk = true;
      #pragma unroll
      for (int j = 0; j < 3; ++j) {
        pk = pk && (sc >= (cs0[j] + cs0[j + 1] + cs0[j + 2]) * (1.0 / 9.0));
        pk = pk && (sc >= (cs2[j] + cs2[j + 1] + cs2[j + 2]) * (1.0 / 9.0));
      }
      pk = pk && (sc >= (cs1[0] + cs1[1] + cs1[2]) * (1.0 / 9.0));
      pk = pk && (sc >= (cs1[2] + cs1[3] + cs1[4]) * (1.0 / 9.0));
      if (!pk) continue;
      if (!(val > 0.1)) continue;

      float fv = convr[(size_t)b * HW + p];
      if (__float_as_uint(fv) < cutb) continue;

      if (lane == 0) {
        u32 pos = atomicAdd(&misc[16 + b], 1u);
        if (pos < KEYCAP) keybuf[(size_t)b * KEYCAP + pos] = make_key(val, p);
      }
    }
  }
}

// ---------------- per-batch bitonic sort of keyed set -> center_pred ----------
__global__ __launch_bounds__(1024) void sort_out_kernel(
    const u64* __restrict__ keybuf, const u32* __restrict__ misc,
    const float* __restrict__ convr, float* __restrict__ center)
{
  __shared__ u64 sk[KEYCAP];
  int b = blockIdx.x;
  int tid = threadIdx.x;
  int M = (int)min(misc[16 + b], (u32)KEYCAP);
  const u64* kb = keybuf + (size_t)b * KEYCAP;
  for (int i = tid; i < KEYCAP; i += 1024) sk[i] = (i < M) ? kb[i] : 0ULL;

  for (int k = 2; k <= KEYCAP; k <<= 1) {
    for (int j = k >> 1; j > 0; j >>= 1) {
      __syncthreads();
      for (int i = tid; i < KEYCAP; i += 1024) {
        int l = i ^ j;
        if (l > i) {
          u64 a = sk[i], bb = sk[l];
          bool up = ((i & k) == 0);
          bool sw = up ? (a < bb) : (a > bb);
          if (sw) { sk[i] = bb; sk[l] = a; }
        }
      }
    }
  }
  __syncthreads();

  for (int i = tid; i < KTOP; i += 1024) {
    float* o = center + ((size_t)b * KTOP + i) * 5;
    if (i < M) {
      u64 key = sk[i];
      u32 p = (~(u32)key) & 0xFFFFFu;
      float v = convr[(size_t)b * HW + p];
      o[0] = 1.0f;
      o[1] = (float)(p & (W - 1));
      o[2] = (float)(p >> 10);
      o[3] = v;
      o[4] = v;
    } else {
      o[0] = 0.f; o[1] = 0.f; o[2] = 0.f; o[3] = 0.f; o[4] = 0.f;
    }
  }
}

extern "C" void kernel_launch(void* const* d_in, const int* in_sizes, int n_in,
                              void* d_out, int out_size, void* d_ws, size_t ws_size,
                              hipStream_t stream) {
  const float* in  = (const float*)d_in[0];
  const float* wc  = (const float*)d_in[1];
  const float* wsw = (const float*)d_in[2];

  float* out0   = (float*)d_out;                     // (8,3,1024,1024)
  float* center = out0 + (size_t)BATCH * 3 * HW;     // (8,2048,5)
  float* convr  = center + (size_t)BATCH * KTOP * 5; // (8,1,1024,1024)

  char* w = (char*)d_ws;
  u32* misc      = (u32*)(w + OFF_MISC);
  u32* hist      = (u32*)(w + OFF_HIST);
  u32* passlist  = (u32*)(w + OFF_PASS);
  u32* checklist = (u32*)(w + OFF_CHK);
  u64* keybuf    = (u64*)(w + OFF_KEY);

  hipMemsetAsync(w, 0, OFF_PASS, stream);  // misc + hist

  conv_screen_kernel<<<dim3(W / TOX, H / TOY, BATCH), 256, 0, stream>>>(
      in, wc, wsw, out0, convr, passlist, checklist, hist, misc);
  cutscan_kernel<<<BATCH, 1024, 0, stream>>>(hist, misc);
  keygen_kernel<<<2048, 256, 0, stream>>>(in, wc, wsw, convr, passlist, misc, keybuf);
  recheck_kernel<<<1024, 256, 0, stream>>>(in, wc, wsw, convr, checklist, misc, keybuf);
  sort_out_kernel<<<BATCH, 1024, 0, stream>>>(keybuf, misc, convr, center);
}

// Round 11
// 595.112 us; speedup vs baseline: 3.0580x; 3.0580x over previous
//
#include <hip/hip_runtime.h>
#include <cstdint>

typedef unsigned int u32;
typedef unsigned long long u64;

#define BATCH 8
#define H 1024
#define W 1024
#define HW (H*W)
#define NPIX (BATCH*HW)
#define KTOP 2048
#define NBIN 8192
#define KEYCAP 8192
#define CAPP 131072
#define CAPC 65536
#define TARGET 2080

#define D9 1e-3f
#define DV 1e-4f

// fused tile geometry
#define TOX 64
#define TOY 32
#define CCX 72
#define CCY 36
#define SCSTR 73
#define SIROWS 68
#define SICOLS 104
#define SISTR 104
#define NIT 11
#define CAPB 768            // LDS append buffer entries per list

// padded misc layout (u32 indices, 64B apart per batch):
//   passcnt[b] = misc[b*16]        chkcnt[b] = misc[128 + b*16]
//   kcnt[b]    = misc[256 + b*16]  cut[b]    = misc[384 + b*16]
#define MP(b) ((b)*16)
#define MC(b) (128 + (b)*16)
#define MK(b) (256 + (b)*16)
#define MT(b) (384 + (b)*16)

// ws layout (bytes); [0, OFF_PASS) memset to 0 each launch
#define OFF_MISC 0                          // u32[1024] padded counters
#define OFF_HIST 4096                       // u32[8][NBIN] = 256 KB
#define OFF_PASS (OFF_HIST + BATCH*NBIN*4)
#define OFF_CHK  (OFF_PASS + BATCH*CAPP*4)
#define OFF_KEY  (OFF_CHK  + BATCH*CAPC*4)

#define LD4(p) (*reinterpret_cast<const float4*>(p))
#define ST4(p,v) (*reinterpret_cast<float4*>(p) = (v))

// ---------------- f64 dilated conv + relu (IDENTICAL to green rounds 3-10) ----------------
__device__ __forceinline__ double conv_resp_f64(
    const float* __restrict__ in, const float* __restrict__ wc,
    const float* __restrict__ wsw, int b, int y, int x)
{
  const float* base = in + (size_t)b * 3 * HW;
  const float* Sp = base;
  const float* Cp = base + HW;
  double resp = 0.0;
  const int dil[3] = {1, 4, 16};
  #pragma unroll
  for (int di = 0; di < 3; ++di) {
    int d = dil[di];
    double ac = 0.0, as = 0.0;
    #pragma unroll
    for (int ky = 0; ky < 3; ++ky) {
      int yy = y + (ky - 1) * d;
      bool yok = ((unsigned)yy < (unsigned)H);
      #pragma unroll
      for (int kx = 0; kx < 3; ++kx) {
        int xx = x + (kx - 1) * d;
        bool ok = yok && ((unsigned)xx < (unsigned)W);
        double a  = ok ? (double)Cp[yy * W + xx] : 0.0;
        double s2 = ok ? (double)Sp[yy * W + xx] : 0.0;
        ac = fma(a,  (double)wc[di * 9 + ky * 3 + kx], ac);
        as = fma(s2, (double)wsw[di * 9 + ky * 3 + kx], as);
      }
    }
    resp += ac;
    resp += as;
  }
  return resp > 0.0 ? resp : 0.0;
}

__device__ __forceinline__ u64 make_key(double val, int p) {
  u64 dbits = __double_as_longlong(val);
  return (dbits & ~0xFFFFFull) | (u64)((~(u32)p) & 0xFFFFFu);
}

// ---------------- stage one channel into LDS with zero-filled halo ----------------
__device__ __forceinline__ void stage_ch(
    float* sIn, const float* __restrict__ src, int tx0, int ty0, int tid)
{
  const int NG = (SIROWS * SICOLS) / 4;
  for (int g = tid; g < NG; g += 256) {
    int r = g / (SICOLS / 4);
    int c4 = (g - r * (SICOLS / 4)) * 4;
    int gy = ty0 - 18 + r;
    int gx0 = tx0 - 20 + c4;
    float4 v = make_float4(0.f, 0.f, 0.f, 0.f);
    if ((unsigned)gy < (unsigned)H) {
      if (gx0 >= 0 && gx0 + 3 < W) {
        v = LD4(src + gy * W + gx0);
      } else {
        float t[4];
        #pragma unroll
        for (int i = 0; i < 4; ++i) {
          int gx = gx0 + i;
          t[i] = ((unsigned)gx < (unsigned)W) ? src[gy * W + gx] : 0.f;
        }
        v = make_float4(t[0], t[1], t[2], t[3]);
      }
    }
    *reinterpret_cast<float4*>(&sIn[r * SISTR + c4]) = v;
  }
}

// ---------------- accumulate 27 taps (one channel) from LDS into part[] ----------------
__device__ __forceinline__ void accum_taps(
    const float* sIn, const float* __restrict__ wp, float* part, int tid)
{
  #pragma unroll
  for (int k = 0; k < NIT; ++k) {
    int idx = k * 256 + tid;
    if (idx < CCX * CCY) {
      int cr = idx / CCX;
      int cc = idx - cr * CCX;
      float a = 0.f;
      #pragma unroll
      for (int di = 0; di < 3; ++di) {
        const int d = (di == 0) ? 1 : (di == 1) ? 4 : 16;
        float ac = 0.f;
        #pragma unroll
        for (int ky = 0; ky < 3; ++ky) {
          const float* rp = sIn + (cr + 16 + (ky - 1) * d) * SISTR + cc + 16;
          float t0 = rp[-d];
          float t1 = rp[0];
          float t2 = rp[d];
          ac = fmaf(t0, wp[di * 9 + ky * 3 + 0], ac);
          ac = fmaf(t1, wp[di * 9 + ky * 3 + 1], ac);
          ac = fmaf(t2, wp[di * 9 + ky * 3 + 2], ac);
        }
        a += ac;
      }
      part[k] += a;
    }
  }
}

// ---------------- fused kernel: staged conv + outputs + screen (block-local appends) -------
__global__ __launch_bounds__(256) void conv_screen_kernel(
    const float* __restrict__ in, const float* __restrict__ wc,
    const float* __restrict__ wsw, float* __restrict__ out0,
    float* __restrict__ convr, u32* __restrict__ passlist,
    u32* __restrict__ checklist, u32* __restrict__ hist, u32* __restrict__ misc)
{
  __shared__ float sIn[SIROWS * SISTR];
  __shared__ float sconv[CCY][SCSTR];

  int b = blockIdx.z;
  int tx0 = blockIdx.x * TOX;
  int ty0 = blockIdx.y * TOY;
  int tid = threadIdx.x;
  const float* Sp = in + (size_t)b * 3 * HW;
  const float* Cp = Sp + HW;
  const float* Rp = Sp + 2 * HW;
  float* ob = out0 + (size_t)b * 3 * HW;
  float* cb = convr + (size_t)b * HW;

  // ---- elementwise outputs for the 64x32 tile (f4) ----
  #pragma unroll
  for (int r = 0; r < (TOX * TOY) / 4 / 256; ++r) {
    int idx = r * 256 + tid;
    int ly = idx / (TOX / 4);
    int lx4 = (idx - ly * (TOX / 4)) * 4;
    int p0 = (ty0 + ly) * W + tx0 + lx4;
    float4 S4 = LD4(Sp + p0);
    float4 C4 = LD4(Cp + p0);
    float4 R4 = LD4(Rp + p0);
    ST4(ob + p0, S4);
    ST4(ob + HW + p0, C4);
    float4 E4 = make_float4(expf(R4.x) - 1.f, expf(R4.y) - 1.f,
                            expf(R4.z) - 1.f, expf(R4.w) - 1.f);
    ST4(ob + 2 * HW + p0, E4);
  }

  // ---- conv: phase A (C), phase B (S) ----
  float part[NIT];
  #pragma unroll
  for (int k = 0; k < NIT; ++k) part[k] = 0.f;

  stage_ch(sIn, Cp, tx0, ty0, tid);
  __syncthreads();
  accum_taps(sIn, wc, part, tid);
  __syncthreads();
  stage_ch(sIn, Sp, tx0, ty0, tid);
  __syncthreads();
  accum_taps(sIn, wsw, part, tid);

  // ---- finalize: relu -> sconv (+ global convr core) ----
  #pragma unroll
  for (int k = 0; k < NIT; ++k) {
    int idx = k * 256 + tid;
    if (idx < CCX * CCY) {
      int cr = idx / CCX;
      int cc = idx - cr * CCX;
      float rv = fmaxf(part[k], 0.f);
      sconv[cr][cc] = rv;
      if (cr >= 2 && cr <= CCY - 3 && cc >= 4 && cc <= CCX - 5) {
        int gy = ty0 - 2 + cr, gx = tx0 - 4 + cc;
        cb[gy * W + gx] = rv;
      }
    }
  }
  __syncthreads();   // sIn dead from here; reuse as append buffers

  u32* pbuf = (u32*)sIn;                 // [CAPB]
  float* pval = (float*)(sIn + CAPB);    // [CAPB]
  u32* cbuf = (u32*)(sIn + 2 * CAPB);    // [CAPB]
  u32* lcnt = (u32*)(sIn + 3 * CAPB);    // [0]=pass [1]=chk [2]=pbase [3]=cbase
  if (tid < 4) lcnt[tid] = 0;
  __syncthreads();

  // ---- in-LDS screen, block-local appends ----
  for (int r = 0; r < (TOX * TOY) / 256; ++r) {
    int idx = r * 256 + tid;
    int ly = idx >> 6;
    int lx = idx & 63;
    int x = tx0 + lx, y = ty0 + ly;
    bool act = (y >= 5 && y <= H - 6 && x >= 5 && x <= W - 6);

    bool cand = false, pass = false;
    float val = 0.f;
    if (act) {
      float vs0[5], vs1[5], vs2[5];
      #pragma unroll
      for (int j = 0; j < 5; ++j) {
        int c = lx + 2 + j;
        float a0 = sconv[ly + 0][c];
        float a1 = sconv[ly + 1][c];
        float a2 = sconv[ly + 2][c];
        float a3 = sconv[ly + 3][c];
        float a4 = sconv[ly + 4][c];
        vs0[j] = a0 + a1 + a2;
        vs1[j] = a1 + a2 + a3;
        vs2[j] = a2 + a3 + a4;
      }
      float hs0[3], hs1[3], hs2[3];
      #pragma unroll
      for (int j = 0; j < 3; ++j) {
        hs0[j] = vs0[j] + vs0[j + 1] + vs0[j + 2];
        hs1[j] = vs1[j] + vs1[j + 1] + vs1[j + 2];
        hs2[j] = vs2[j] + vs2[j + 1] + vs2[j + 2];
      }
      float sc9 = hs1[1];
      val = sconv[ly + 2][lx + 4];
      float m9 = fmaxf(fmaxf(fmaxf(hs0[0], hs0[1]), fmaxf(hs0[2], hs1[0])),
                       fmaxf(fmaxf(hs1[2], hs2[0]), fmaxf(hs2[1], hs2[2])));
      cand = !((sc9 < 0.9f - D9) || (sc9 < m9 - D9) || (val < 0.1f - DV));
      pass = cand && (sc9 > 0.9f + D9) && (sc9 >= m9 + D9) && (val > 0.1f + DV);
    }

    if (pass) {
      u32 pos = atomicAdd(&lcnt[0], 1u);
      if (pos < CAPB) { pbuf[pos] = (u32)(y * W + x); pval[pos] = val; }
      else {           // rare overflow: direct global append
        u32 g = atomicAdd(&misc[MP(b)], 1u);
        if (g < CAPP) passlist[(size_t)b * CAPP + g] = (u32)(y * W + x);
        atomicAdd(&hist[b * NBIN + (__float_as_uint(val) >> 19)], 1u);
      }
    } else if (cand) {
      u32 pos = atomicAdd(&lcnt[1], 1u);
      if (pos < CAPB) cbuf[pos] = (u32)(y * W + x);
      else {
        u32 g = atomicAdd(&misc[MC(b)], 1u);
        if (g < CAPC) checklist[(size_t)b * CAPC + g] = (u32)(y * W + x);
      }
    }
  }
  __syncthreads();

  u32 np = min(lcnt[0], (u32)CAPB);
  u32 nc = min(lcnt[1], (u32)CAPB);
  if (tid == 0) lcnt[2] = np ? atomicAdd(&misc[MP(b)], np) : 0u;
  if (tid == 1) lcnt[3] = nc ? atomicAdd(&misc[MC(b)], nc) : 0u;
  __syncthreads();
  u32 pbase = lcnt[2], cbase = lcnt[3];

  for (u32 i = tid; i < np; i += 256) {
    u32 g = pbase + i;
    if (g < CAPP) passlist[(size_t)b * CAPP + g] = pbuf[i];
    atomicAdd(&hist[b * NBIN + (__float_as_uint(pval[i]) >> 19)], 1u);
  }
  for (u32 i = tid; i < nc; i += 256) {
    u32 g = cbase + i;
    if (g < CAPC) checklist[(size_t)b * CAPC + g] = cbuf[i];
  }
}

// ---------------- suffix-scan hist -> f32 cut (rank TARGET, one-bin slack) ------
__global__ __launch_bounds__(1024) void cutscan_kernel(
    const u32* __restrict__ hist, u32* __restrict__ misc)
{
  __shared__ u32 sfx[NBIN];
  int b = blockIdx.x;
  int tid = threadIdx.x;
  const u32* h = hist + b * NBIN;
  #pragma unroll
  for (int k = 0; k < 8; ++k) sfx[tid * 8 + k] = h[tid * 8 + k];
  __syncthreads();

  for (int off = 1; off < NBIN; off <<= 1) {
    u32 t[8];
    #pragma unroll
    for (int k = 0; k < 8; ++k) {
      int i = tid * 8 + k;
      t[k] = (i + off < NBIN) ? sfx[i + off] : 0u;
    }
    __syncthreads();
    #pragma unroll
    for (int k = 0; k < 8; ++k) sfx[tid * 8 + k] += t[k];
    __syncthreads();
  }

  if (sfx[0] < TARGET) return;

  #pragma unroll
  for (int k = 0; k < 8; ++k) {
    int i = tid * 8 + k;
    u32 s = sfx[i];
    u32 nxt = (i + 1 < NBIN) ? sfx[i + 1] : 0u;
    if (s >= TARGET && nxt < TARGET) {
      u32 cutbin = (i > 0) ? (u32)(i - 1) : 0u;
      misc[MT(b)] = cutbin << 19;
    }
  }
}

// ---------------- exact f64 keys for pass-peaks above cut (ballot-aggregated) -------------
__global__ __launch_bounds__(256) void keygen_kernel(
    const float* __restrict__ in, const float* __restrict__ wc,
    const float* __restrict__ wsw, const float* __restrict__ convr,
    const u32* __restrict__ passlist, u32* __restrict__ misc, u64* __restrict__ keybuf)
{
  int gtid = blockIdx.x * 256 + threadIdx.x;
  int gsz = gridDim.x * 256;
  int lane = threadIdx.x & 63;
  for (int b = 0; b < BATCH; ++b) {
    int np = (int)min(misc[MP(b)], (u32)CAPP);
    u32 cutb = misc[MT(b)];
    for (int i = gtid; i < np; i += gsz) {
      int p = (int)passlist[(size_t)b * CAPP + i];
      float fv = convr[(size_t)b * HW + p];
      bool keep = (__float_as_uint(fv) >= cutb);
      u64 k64 = 0;
      if (keep) k64 = make_key(conv_resp_f64(in, wc, wsw, b, p >> 10, p & (W - 1)), p);
      u64 km = __ballot(keep);
      if (keep) {
        int leader = __ffsll((unsigned long long)km) - 1;
        u32 base = 0;
        if (lane == leader) base = atomicAdd(&misc[MK(b)], (u32)__popcll(km));
        base = __shfl(base, leader);
        u32 rk = (u32)__popcll(km & ((1ull << lane) - 1ull));
        if (base + rk < KEYCAP) keybuf[(size_t)b * KEYCAP + base + rk] = k64;
      }
    }
  }
}

// ---------------- exact f64 recheck, one wave per uncertain pixel ----------------
__global__ __launch_bounds__(256) void recheck_kernel(
    const float* __restrict__ in, const float* __restrict__ wc,
    const float* __restrict__ wsw, const float* __restrict__ convr,
    const u32* __restrict__ checklist, u32* __restrict__ misc, u64* __restrict__ keybuf)
{
  int wid = (blockIdx.x * 256 + threadIdx.x) >> 6;
  int lane = threadIdx.x & 63;
  int nw = (gridDim.x * 256) >> 6;

  for (int b = 0; b < BATCH; ++b) {
    int nc = (int)min(misc[MC(b)], (u32)CAPC);
    u32 cutb = misc[MT(b)];
    for (int i = wid; i < nc; i += nw) {
      int p = (int)checklist[(size_t)b * CAPC + i];
      int y = p >> 10, x = p & (W - 1);

      double v = 0.0;
      if (lane < 25)
        v = conv_resp_f64(in, wc, wsw, b, y + lane / 5 - 2, x + lane % 5 - 2);

      double c[25];
      #pragma unroll
      for (int k = 0; k < 25; ++k) c[k] = __shfl(v, k);

      double cs0[5], cs1[5], cs2[5];
      #pragma unroll
      for (int j = 0; j < 5; ++j) {
        cs0[j] = c[0 + j] + c[5 + j] + c[10 + j];
        cs1[j] = c[5 + j] + c[10 + j] + c[15 + j];
        cs2[j] = c[10 + j] + c[15 + j] + c[20 + j];
      }
      double val = c[12];

      double sc = (cs1[1] + cs1[2] + cs1[3]) * (1.0 / 9.0);
      if (!(sc > 0.1)) continue;
      bool pk = true;
      #pragma unroll
      for (int j = 0; j < 3; ++j) {
        pk = pk && (sc >= (cs0[j] + cs0[j + 1] + cs0[j + 2]) * (1.0 / 9.0));
        pk = pk && (sc >= (cs2[j] + cs2[j + 1] + cs2[j + 2]) * (1.0 / 9.0));
      }
      pk = pk && (sc >= (cs1[0] + cs1[1] + cs1[2]) * (1.0 / 9.0));
      pk = pk && (sc >= (cs1[2] + cs1[3] + cs1[4]) * (1.0 / 9.0));
      if (!pk) continue;
      if (!(val > 0.1)) continue;

      float fv = convr[(size_t)b * HW + p];
      if (__float_as_uint(fv) < cutb) continue;

      if (lane == 0) {
        u32 pos = atomicAdd(&misc[MK(b)], 1u);
        if (pos < KEYCAP) keybuf[(size_t)b * KEYCAP + pos] = make_key(val, p);
      }
    }
  }
}

// ---------------- per-batch bitonic sort of keyed set -> center_pred ----------
__global__ __launch_bounds__(1024) void sort_out_kernel(
    const u64* __restrict__ keybuf, const u32* __restrict__ misc,
    const float* __restrict__ convr, float* __restrict__ center)
{
  __shared__ u64 sk[KEYCAP];
  int b = blockIdx.x;
  int tid = threadIdx.x;
  int M = (int)min(misc[MK(b)], (u32)KEYCAP);
  const u64* kb = keybuf + (size_t)b * KEYCAP;
  for (int i = tid; i < KEYCAP; i += 1024) sk[i] = (i < M) ? kb[i] : 0ULL;

  for (int k = 2; k <= KEYCAP; k <<= 1) {
    for (int j = k >> 1; j > 0; j >>= 1) {
      __syncthreads();
      for (int i = tid; i < KEYCAP; i += 1024) {
        int l = i ^ j;
        if (l > i) {
          u64 a = sk[i], bb = sk[l];
          bool up = ((i & k) == 0);
          bool sw = up ? (a < bb) : (a > bb);
          if (sw) { sk[i] = bb; sk[l] = a; }
        }
      }
    }
  }
  __syncthreads();

  for (int i = tid; i < KTOP; i += 1024) {
    float* o = center + ((size_t)b * KTOP + i) * 5;
    if (i < M) {
      u64 key = sk[i];
      u32 p = (~(u32)key) & 0xFFFFFu;
      float v = convr[(size_t)b * HW + p];
      o[0] = 1.0f;
      o[1] = (float)(p & (W - 1));
      o[2] = (float)(p >> 10);
      o[3] = v;
      o[4] = v;
    } else {
      o[0] = 0.f; o[1] = 0.f; o[2] = 0.f; o[3] = 0.f; o[4] = 0.f;
    }
  }
}

extern "C" void kernel_launch(void* const* d_in, const int* in_sizes, int n_in,
                              void* d_out, int out_size, void* d_ws, size_t ws_size,
                              hipStream_t stream) {
  const float* in  = (const float*)d_in[0];
  const float* wc  = (const float*)d_in[1];
  const float* wsw = (const float*)d_in[2];

  float* out0   = (float*)d_out;                     // (8,3,1024,1024)
  float* center = out0 + (size_t)BATCH * 3 * HW;     // (8,2048,5)
  float* convr  = center + (size_t)BATCH * KTOP * 5; // (8,1,1024,1024)

  char* w = (char*)d_ws;
  u32* misc      = (u32*)(w + OFF_MISC);
  u32* hist      = (u32*)(w + OFF_HIST);
  u32* passlist  = (u32*)(w + OFF_PASS);
  u32* checklist = (u32*)(w + OFF_CHK);
  u64* keybuf    = (u64*)(w + OFF_KEY);

  hipMemsetAsync(w, 0, OFF_PASS, stream);  // misc + hist

  conv_screen_kernel<<<dim3(W / TOX, H / TOY, BATCH), 256, 0, stream>>>(
      in, wc, wsw, out0, convr, passlist, checklist, hist, misc);
  cutscan_kernel<<<BATCH, 1024, 0, stream>>>(hist, misc);
  keygen_kernel<<<2048, 256, 0, stream>>>(in, wc, wsw, convr, passlist, misc, keybuf);
  recheck_kernel<<<1024, 256, 0, stream>>>(in, wc, wsw, convr, checklist, misc, keybuf);
  sort_out_kernel<<<BATCH, 1024, 0, stream>>>(keybuf, misc, convr, center);
}

// Round 12
// 378.130 us; speedup vs baseline: 4.8128x; 1.5738x over previous
//
#include <hip/hip_runtime.h>
#include <cstdint>

typedef unsigned int u32;
typedef unsigned long long u64;

#define BATCH 8
#define H 1024
#define W 1024
#define HW (H*W)
#define NPIX (BATCH*HW)
#define KTOP 2048
#define NBIN 8192
#define KEYCAP 8192
#define CAPP 131072
#define CAPC 65536
#define TARGET 2080

#define D9 1e-3f
#define DV 1e-4f

// fused tile geometry
#define TOX 64
#define TOY 32
#define CCX 72
#define CCY 36
#define SCSTR 73
#define SIROWS 68
#define SICOLS 104
#define SISTR 104
#define NIT 11
#define CAPB 768

// padded misc counters (64B apart)
#define MP(b) ((b)*16)
#define MC(b) (128 + (b)*16)
#define MK(b) (256 + (b)*16)
#define MT(b) (384 + (b)*16)

// ws layout (bytes); [0, OFF_PASS) memset to 0 each launch
#define OFF_MISC 0
#define OFF_HIST 4096
#define OFF_PASS (OFF_HIST + BATCH*NBIN*4)
#define OFF_CHK  (OFF_PASS + (size_t)BATCH*CAPP*8)
#define OFF_KEY  (OFF_CHK  + (size_t)BATCH*CAPC*8)

#define LD4(p) (*reinterpret_cast<const float4*>(p))
#define ST4(p,v) (*reinterpret_cast<float4*>(p) = (v))

// ---------------- f64 dilated conv + relu (IDENTICAL to green rounds 3-11) ----------------
__device__ __forceinline__ double conv_resp_f64(
    const float* __restrict__ in, const float* __restrict__ wc,
    const float* __restrict__ wsw, int b, int y, int x)
{
  const float* base = in + (size_t)b * 3 * HW;
  const float* Sp = base;
  const float* Cp = base + HW;
  double resp = 0.0;
  const int dil[3] = {1, 4, 16};
  #pragma unroll
  for (int di = 0; di < 3; ++di) {
    int d = dil[di];
    double ac = 0.0, as = 0.0;
    #pragma unroll
    for (int ky = 0; ky < 3; ++ky) {
      int yy = y + (ky - 1) * d;
      bool yok = ((unsigned)yy < (unsigned)H);
      #pragma unroll
      for (int kx = 0; kx < 3; ++kx) {
        int xx = x + (kx - 1) * d;
        bool ok = yok && ((unsigned)xx < (unsigned)W);
        double a  = ok ? (double)Cp[yy * W + xx] : 0.0;
        double s2 = ok ? (double)Sp[yy * W + xx] : 0.0;
        ac = fma(a,  (double)wc[di * 9 + ky * 3 + kx], ac);
        as = fma(s2, (double)wsw[di * 9 + ky * 3 + kx], as);
      }
    }
    resp += ac;
    resp += as;
  }
  return resp > 0.0 ? resp : 0.0;
}

__device__ __forceinline__ u64 make_key(double val, int p) {
  u64 dbits = __double_as_longlong(val);
  return (dbits & ~0xFFFFFull) | (u64)((~(u32)p) & 0xFFFFFu);
}

// ---------------- stage one channel into LDS with zero-filled halo ----------------
__device__ __forceinline__ void stage_ch(
    float* sIn, const float* __restrict__ src, int tx0, int ty0, int tid)
{
  const int NG = (SIROWS * SICOLS) / 4;
  for (int g = tid; g < NG; g += 256) {
    int r = g / (SICOLS / 4);
    int c4 = (g - r * (SICOLS / 4)) * 4;
    int gy = ty0 - 18 + r;
    int gx0 = tx0 - 20 + c4;
    float4 v = make_float4(0.f, 0.f, 0.f, 0.f);
    if ((unsigned)gy < (unsigned)H) {
      if (gx0 >= 0 && gx0 + 3 < W) {
        v = LD4(src + gy * W + gx0);
      } else {
        float t[4];
        #pragma unroll
        for (int i = 0; i < 4; ++i) {
          int gx = gx0 + i;
          t[i] = ((unsigned)gx < (unsigned)W) ? src[gy * W + gx] : 0.f;
        }
        v = make_float4(t[0], t[1], t[2], t[3]);
      }
    }
    *reinterpret_cast<float4*>(&sIn[r * SISTR + c4]) = v;
  }
}

// ---------------- accumulate 27 taps (one channel) from LDS into part[] ----------------
__device__ __forceinline__ void accum_taps(
    const float* sIn, const float* __restrict__ wp, float* part, int tid)
{
  #pragma unroll
  for (int k = 0; k < NIT; ++k) {
    int idx = k * 256 + tid;
    if (idx < CCX * CCY) {
      int cr = idx / CCX;
      int cc = idx - cr * CCX;
      float a = 0.f;
      #pragma unroll
      for (int di = 0; di < 3; ++di) {
        const int d = (di == 0) ? 1 : (di == 1) ? 4 : 16;
        float ac = 0.f;
        #pragma unroll
        for (int ky = 0; ky < 3; ++ky) {
          const float* rp = sIn + (cr + 16 + (ky - 1) * d) * SISTR + cc + 16;
          float t0 = rp[-d];
          float t1 = rp[0];
          float t2 = rp[d];
          ac = fmaf(t0, wp[di * 9 + ky * 3 + 0], ac);
          ac = fmaf(t1, wp[di * 9 + ky * 3 + 1], ac);
          ac = fmaf(t2, wp[di * 9 + ky * 3 + 2], ac);
        }
        a += ac;
      }
      part[k] += a;
    }
  }
}

// ---------------- fused kernel: staged conv + outputs + screen ----------------
// LDS union: phase 1: sIn[68*104]=28288B; phase 2 (after barrier): sconv[36][73]
// (10512B) + u64 append buffers + counters, all within the same 28288B region.
__global__ __launch_bounds__(256) void conv_screen_kernel(
    const float* __restrict__ in, const float* __restrict__ wc,
    const float* __restrict__ wsw, float* __restrict__ out0,
    float* __restrict__ convr, u64* __restrict__ passlist,
    u64* __restrict__ checklist, u32* __restrict__ hist, u32* __restrict__ misc)
{
  __shared__ float uni[SIROWS * SISTR];   // 7072 floats = 28288 B

  float* sIn = uni;
  float (*sconv)[SCSTR] = (float (*)[SCSTR])uni;       // 2628 floats
  u64* pbuf = (u64*)(uni + 2632);                      // 768 u64
  u64* cbuf = (u64*)(uni + 2632 + 2 * CAPB);           // 768 u64
  u32* lcnt = (u32*)(uni + 2632 + 4 * CAPB);           // 4 u32

  int b = blockIdx.z;
  int tx0 = blockIdx.x * TOX;
  int ty0 = blockIdx.y * TOY;
  int tid = threadIdx.x;
  const float* Sp = in + (size_t)b * 3 * HW;
  const float* Cp = Sp + HW;
  const float* Rp = Sp + 2 * HW;
  float* ob = out0 + (size_t)b * 3 * HW;
  float* cb = convr + (size_t)b * HW;

  // ---- elementwise outputs (f4) ----
  #pragma unroll
  for (int r = 0; r < (TOX * TOY) / 4 / 256; ++r) {
    int idx = r * 256 + tid;
    int ly = idx / (TOX / 4);
    int lx4 = (idx - ly * (TOX / 4)) * 4;
    int p0 = (ty0 + ly) * W + tx0 + lx4;
    float4 S4 = LD4(Sp + p0);
    float4 C4 = LD4(Cp + p0);
    float4 R4 = LD4(Rp + p0);
    ST4(ob + p0, S4);
    ST4(ob + HW + p0, C4);
    float4 E4 = make_float4(expf(R4.x) - 1.f, expf(R4.y) - 1.f,
                            expf(R4.z) - 1.f, expf(R4.w) - 1.f);
    ST4(ob + 2 * HW + p0, E4);
  }

  // ---- conv: phase A (C), phase B (S) ----
  float part[NIT];
  #pragma unroll
  for (int k = 0; k < NIT; ++k) part[k] = 0.f;

  stage_ch(sIn, Cp, tx0, ty0, tid);
  __syncthreads();
  accum_taps(sIn, wc, part, tid);
  __syncthreads();
  stage_ch(sIn, Sp, tx0, ty0, tid);
  __syncthreads();
  accum_taps(sIn, wsw, part, tid);
  __syncthreads();                     // sIn dead; region becomes sconv+buffers

  // ---- finalize: relu -> sconv (+ global convr core); init counters ----
  if (tid < 4) lcnt[tid] = 0;
  #pragma unroll
  for (int k = 0; k < NIT; ++k) {
    int idx = k * 256 + tid;
    if (idx < CCX * CCY) {
      int cr = idx / CCX;
      int cc = idx - cr * CCX;
      float rv = fmaxf(part[k], 0.f);
      sconv[cr][cc] = rv;
      if (cr >= 2 && cr <= CCY - 3 && cc >= 4 && cc <= CCX - 5) {
        int gy = ty0 - 2 + cr, gx = tx0 - 4 + cc;
        cb[gy * W + gx] = rv;
      }
    }
  }
  __syncthreads();

  // ---- in-LDS screen, block-local u64 appends ----
  for (int r = 0; r < (TOX * TOY) / 256; ++r) {
    int idx = r * 256 + tid;
    int ly = idx >> 6;
    int lx = idx & 63;
    int x = tx0 + lx, y = ty0 + ly;
    bool act = (y >= 5 && y <= H - 6 && x >= 5 && x <= W - 6);

    bool cand = false, pass = false;
    float val = 0.f;
    if (act) {
      float vs0[5], vs1[5], vs2[5];
      #pragma unroll
      for (int j = 0; j < 5; ++j) {
        int c = lx + 2 + j;
        float a0 = sconv[ly + 0][c];
        float a1 = sconv[ly + 1][c];
        float a2 = sconv[ly + 2][c];
        float a3 = sconv[ly + 3][c];
        float a4 = sconv[ly + 4][c];
        vs0[j] = a0 + a1 + a2;
        vs1[j] = a1 + a2 + a3;
        vs2[j] = a2 + a3 + a4;
      }
      float hs0[3], hs1[3], hs2[3];
      #pragma unroll
      for (int j = 0; j < 3; ++j) {
        hs0[j] = vs0[j] + vs0[j + 1] + vs0[j + 2];
        hs1[j] = vs1[j] + vs1[j + 1] + vs1[j + 2];
        hs2[j] = vs2[j] + vs2[j + 1] + vs2[j + 2];
      }
      float sc9 = hs1[1];
      val = sconv[ly + 2][lx + 4];
      float m9 = fmaxf(fmaxf(fmaxf(hs0[0], hs0[1]), fmaxf(hs0[2], hs1[0])),
                       fmaxf(fmaxf(hs1[2], hs2[0]), fmaxf(hs2[1], hs2[2])));
      cand = !((sc9 < 0.9f - D9) || (sc9 < m9 - D9) || (val < 0.1f - DV));
      pass = cand && (sc9 > 0.9f + D9) && (sc9 >= m9 + D9) && (val > 0.1f + DV);
    }

    u64 entry = ((u64)__float_as_uint(val) << 32) | (u32)(y * W + x);
    if (pass) {
      u32 pos = atomicAdd(&lcnt[0], 1u);
      if (pos < CAPB) pbuf[pos] = entry;
      else {
        u32 g = atomicAdd(&misc[MP(b)], 1u);
        if (g < CAPP) passlist[(size_t)b * CAPP + g] = entry;
        atomicAdd(&hist[b * NBIN + (__float_as_uint(val) >> 19)], 1u);
      }
    } else if (cand) {
      u32 pos = atomicAdd(&lcnt[1], 1u);
      if (pos < CAPB) cbuf[pos] = entry;
      else {
        u32 g = atomicAdd(&misc[MC(b)], 1u);
        if (g < CAPC) checklist[(size_t)b * CAPC + g] = entry;
      }
    }
  }
  __syncthreads();

  u32 np = min(lcnt[0], (u32)CAPB);
  u32 nc = min(lcnt[1], (u32)CAPB);
  if (tid == 0) lcnt[2] = np ? atomicAdd(&misc[MP(b)], np) : 0u;
  if (tid == 1) lcnt[3] = nc ? atomicAdd(&misc[MC(b)], nc) : 0u;
  __syncthreads();
  u32 pbase = lcnt[2], cbase = lcnt[3];

  for (u32 i = tid; i < np; i += 256) {
    u64 e = pbuf[i];
    u32 g = pbase + i;
    if (g < CAPP) passlist[(size_t)b * CAPP + g] = e;
    atomicAdd(&hist[b * NBIN + ((u32)(e >> 32) >> 19)], 1u);
  }
  for (u32 i = tid; i < nc; i += 256) {
    u32 g = cbase + i;
    if (g < CAPC) checklist[(size_t)b * CAPC + g] = cbuf[i];
  }
}

// ---------------- suffix-scan hist -> f32 cut (padded LDS, conflict-free) ------
__global__ __launch_bounds__(1024) void cutscan_kernel(
    const u32* __restrict__ hist, u32* __restrict__ misc)
{
  __shared__ u32 sfx[NBIN + NBIN / 32];
  #define SX(i) sfx[(i) + ((i) >> 5)]
  int b = blockIdx.x;
  int tid = threadIdx.x;
  const u32* h = hist + b * NBIN;
  #pragma unroll
  for (int k = 0; k < 8; ++k) SX(tid * 8 + k) = h[tid * 8 + k];
  __syncthreads();

  for (int off = 1; off < NBIN; off <<= 1) {
    u32 t[8];
    #pragma unroll
    for (int k = 0; k < 8; ++k) {
      int i = tid * 8 + k;
      t[k] = (i + off < NBIN) ? SX(i + off) : 0u;
    }
    __syncthreads();
    #pragma unroll
    for (int k = 0; k < 8; ++k) SX(tid * 8 + k) += t[k];
    __syncthreads();
  }

  if (SX(0) < TARGET) return;

  #pragma unroll
  for (int k = 0; k < 8; ++k) {
    int i = tid * 8 + k;
    u32 s = SX(i);
    u32 nxt = (i + 1 < NBIN) ? SX(i + 1) : 0u;
    if (s >= TARGET && nxt < TARGET) {
      u32 cutbin = (i > 0) ? (u32)(i - 1) : 0u;
      misc[MT(b)] = cutbin << 19;
    }
  }
  #undef SX
}

// ---------------- exact f64 keys for pass-peaks above cut ----------------
__global__ __launch_bounds__(256) void keygen_kernel(
    const float* __restrict__ in, const float* __restrict__ wc,
    const float* __restrict__ wsw, const u64* __restrict__ passlist,
    u32* __restrict__ misc, u64* __restrict__ keybuf)
{
  int b = blockIdx.y;
  int np = (int)min(misc[MP(b)], (u32)CAPP);
  u32 cutb = misc[MT(b)];
  int lane = threadIdx.x & 63;
  int stride = gridDim.x * 256;
  for (int i = blockIdx.x * 256 + threadIdx.x; i < np; i += stride) {
    u64 e = passlist[(size_t)b * CAPP + i];
    bool keep = ((u32)(e >> 32)) >= cutb;
    u64 k64 = 0;
    if (keep) {
      int p = (int)(e & 0xFFFFFu);
      k64 = make_key(conv_resp_f64(in, wc, wsw, b, p >> 10, p & (W - 1)), p);
    }
    u64 km = __ballot(keep);
    if (keep) {
      int leader = __ffsll((unsigned long long)km) - 1;
      u32 base = 0;
      if (lane == leader) base = atomicAdd(&misc[MK(b)], (u32)__popcll(km));
      base = __shfl(base, leader);
      u32 rk = (u32)__popcll(km & ((1ull << lane) - 1ull));
      if (base + rk < KEYCAP) keybuf[(size_t)b * KEYCAP + base + rk] = k64;
    }
  }
}

// ---------------- exact f64 recheck (cut-filter FIRST), wave per survivor ----------------
__global__ __launch_bounds__(256) void recheck_kernel(
    const float* __restrict__ in, const float* __restrict__ wc,
    const float* __restrict__ wsw, const u64* __restrict__ checklist,
    u32* __restrict__ misc, u64* __restrict__ keybuf)
{
  int b = blockIdx.y;
  int nwb = gridDim.x * 4;
  int wid = blockIdx.x * 4 + (threadIdx.x >> 6);
  int lane = threadIdx.x & 63;
  int nc = (int)min(misc[MC(b)], (u32)CAPC);
  u32 cutb = misc[MT(b)];

  for (int i = wid; i < nc; i += nwb) {
    u64 e = checklist[(size_t)b * CAPC + i];
    if (((u32)(e >> 32)) < cutb) continue;   // early rank filter
    int p = (int)(e & 0xFFFFFu);
    int y = p >> 10, x = p & (W - 1);

    double v = 0.0;
    if (lane < 25)
      v = conv_resp_f64(in, wc, wsw, b, y + lane / 5 - 2, x + lane % 5 - 2);

    double c[25];
    #pragma unroll
    for (int k = 0; k < 25; ++k) c[k] = __shfl(v, k);

    double cs0[5], cs1[5], cs2[5];
    #pragma unroll
    for (int j = 0; j < 5; ++j) {
      cs0[j] = c[0 + j] + c[5 + j] + c[10 + j];
      cs1[j] = c[5 + j] + c[10 + j] + c[15 + j];
      cs2[j] = c[10 + j] + c[15 + j] + c[20 + j];
    }
    double val = c[12];

    double sc = (cs1[1] + cs1[2] + cs1[3]) * (1.0 / 9.0);
    if (!(sc > 0.1)) continue;
    bool pk = true;
    #pragma unroll
    for (int j = 0; j < 3; ++j) {
      pk = pk && (sc >= (cs0[j] + cs0[j + 1] + cs0[j + 2]) * (1.0 / 9.0));
      pk = pk && (sc >= (cs2[j] + cs2[j + 1] + cs2[j + 2]) * (1.0 / 9.0));
    }
    pk = pk && (sc >= (cs1[0] + cs1[1] + cs1[2]) * (1.0 / 9.0));
    pk = pk && (sc >= (cs1[2] + cs1[3] + cs1[4]) * (1.0 / 9.0));
    if (!pk) continue;
    if (!(val > 0.1)) continue;

    if (lane == 0) {
      u32 pos = atomicAdd(&misc[MK(b)], 1u);
      if (pos < KEYCAP) keybuf[(size_t)b * KEYCAP + pos] = make_key(val, p);
    }
  }
}

// ---------------- per-batch bitonic sort of keyed set -> center_pred ----------
__global__ __launch_bounds__(1024) void sort_out_kernel(
    const u64* __restrict__ keybuf, const u32* __restrict__ misc,
    const float* __restrict__ convr, float* __restrict__ center)
{
  __shared__ u64 sk[KEYCAP];
  int b = blockIdx.x;
  int tid = threadIdx.x;
  int M = (int)min(misc[MK(b)], (u32)KEYCAP);
  const u64* kb = keybuf + (size_t)b * KEYCAP;
  for (int i = tid; i < KEYCAP; i += 1024) sk[i] = (i < M) ? kb[i] : 0ULL;

  for (int k = 2; k <= KEYCAP; k <<= 1) {
    for (int j = k >> 1; j > 0; j >>= 1) {
      __syncthreads();
      for (int i = tid; i < KEYCAP; i += 1024) {
        int l = i ^ j;
        if (l > i) {
          u64 a = sk[i], bb = sk[l];
          bool up = ((i & k) == 0);
          bool sw = up ? (a < bb) : (a > bb);
          if (sw) { sk[i] = bb; sk[l] = a; }
        }
      }
    }
  }
  __syncthreads();

  for (int i = tid; i < KTOP; i += 1024) {
    float* o = center + ((size_t)b * KTOP + i) * 5;
    if (i < M) {
      u64 key = sk[i];
      u32 p = (~(u32)key) & 0xFFFFFu;
      float v = convr[(size_t)b * HW + p];
      o[0] = 1.0f;
      o[1] = (float)(p & (W - 1));
      o[2] = (float)(p >> 10);
      o[3] = v;
      o[4] = v;
    } else {
      o[0] = 0.f; o[1] = 0.f; o[2] = 0.f; o[3] = 0.f; o[4] = 0.f;
    }
  }
}

extern "C" void kernel_launch(void* const* d_in, const int* in_sizes, int n_in,
                              void* d_out, int out_size, void* d_ws, size_t ws_size,
                              hipStream_t stream) {
  const float* in  = (const float*)d_in[0];
  const float* wc  = (const float*)d_in[1];
  const float* wsw = (const float*)d_in[2];

  float* out0   = (float*)d_out;                     // (8,3,1024,1024)
  float* center = out0 + (size_t)BATCH * 3 * HW;     // (8,2048,5)
  float* convr  = center + (size_t)BATCH * KTOP * 5; // (8,1,1024,1024)

  char* w = (char*)d_ws;
  u32* misc      = (u32*)(w + OFF_MISC);
  u32* hist      = (u32*)(w + OFF_HIST);
  u64* passlist  = (u64*)(w + OFF_PASS);
  u64* checklist = (u64*)(w + OFF_CHK);
  u64* keybuf    = (u64*)(w + OFF_KEY);

  hipMemsetAsync(w, 0, OFF_PASS, stream);  // misc + hist

  conv_screen_kernel<<<dim3(W / TOX, H / TOY, BATCH), 256, 0, stream>>>(
      in, wc, wsw, out0, convr, passlist, checklist, hist, misc);
  cutscan_kernel<<<BATCH, 1024, 0, stream>>>(hist, misc);
  keygen_kernel<<<dim3(64, BATCH), 256, 0, stream>>>(in, wc, wsw, passlist, misc, keybuf);
  recheck_kernel<<<dim3(64, BATCH), 256, 0, stream>>>(in, wc, wsw, checklist, misc, keybuf);
  sort_out_kernel<<<BATCH, 1024, 0, stream>>>(keybuf, misc, convr, center);
}